// Round 13
// baseline (218.863 us; speedup 1.0000x reference)
//
#include <hip/hip_runtime.h>
#include <hip/hip_bf16.h>
#include <stdint.h>

typedef unsigned int U32;
typedef unsigned short U16;

static __device__ __forceinline__ U32 f2bf_rne(float f){
  U32 u; __builtin_memcpy(&u, &f, 4);
  u = (u + 0x7fffu + ((u >> 16) & 1u)) >> 16;
  return u & 0xffffu;
}
static __device__ __forceinline__ float bflo2f(U32 p){
  U32 u = p << 16; float f; __builtin_memcpy(&f, &u, 4); return f;
}
static __device__ __forceinline__ float bfhi2f(U32 p){
  U32 u = p & 0xffff0000u; float f; __builtin_memcpy(&f, &u, 4); return f;
}

// ---------------- fused resize: 4x antialiased bilinear, H then V, one kernel ----------------
__global__ void resize_k(const float* __restrict__ x, float* __restrict__ resz){
  __shared__ float hs[68][64];
  int blk = blockIdx.x;
  int tx = blk & 3;
  int ty = (blk >> 2) & 15;
  int bc = blk >> 6;
  int ox0 = tx << 6, oy0 = ty << 4;
  int r0 = 4*oy0 - 2; if (r0 < 0) r0 = 0;
  if (r0 > 956) r0 = 958;              // last tile: rows 958..1023 (66 used)
  const float* src = x + ((size_t)bc << 20);
  #pragma unroll 4
  for (int i = threadIdx.x; i < 68*64; i += 256){
    int r   = i >> 6;
    int oxl = i & 63;
    int ox  = ox0 + oxl;
    int rr  = r0 + r; if (rr > 1023) rr = 1023;
    const float2* row2 = (const float2*)(src + ((size_t)rr << 10));
    float acc;
    if (ox >= 1 && ox <= 254){
      float2 a = row2[2*ox-1];
      float2 b = row2[2*ox];
      float2 c = row2[2*ox+1];
      float2 d = row2[2*ox+2];
      acc = (1.f/32)*(a.x + d.y)
          + (3.f/32)*(a.y + d.x)
          + (5.f/32)*(b.x + c.y)
          + (7.f/32)*(b.y + c.x);
    } else if (ox == 0){
      float2 a = row2[0], b = row2[1], c = row2[2];
      acc = (0.625f/3.5f)*a.x + (0.875f/3.5f)*a.y
          + (0.875f/3.5f)*b.x + (0.625f/3.5f)*b.y
          + (0.375f/3.5f)*c.x + (0.125f/3.5f)*c.y;
    } else {
      float2 a = row2[509], b = row2[510], c = row2[511];
      acc = (0.125f/3.5f)*a.x + (0.375f/3.5f)*a.y
          + (0.625f/3.5f)*b.x + (0.875f/3.5f)*b.y
          + (0.875f/3.5f)*c.x + (0.625f/3.5f)*c.y;
    }
    hs[r][oxl] = acc;
  }
  __syncthreads();
  for (int i = threadIdx.x; i < 16*64; i += 256){
    int oyl = i >> 6, oxl = i & 63;
    int oy = oy0 + oyl;
    float acc;
    if (oy >= 1 && oy <= 254){
      int j0 = 4*oy - 2 - r0;
      acc = (1.f/32)*(hs[j0+0][oxl] + hs[j0+7][oxl])
          + (3.f/32)*(hs[j0+1][oxl] + hs[j0+6][oxl])
          + (5.f/32)*(hs[j0+2][oxl] + hs[j0+5][oxl])
          + (7.f/32)*(hs[j0+3][oxl] + hs[j0+4][oxl]);
    } else if (oy == 0){     // r0 == 0
      acc = (0.625f/3.5f)*hs[0][oxl] + (0.875f/3.5f)*hs[1][oxl]
          + (0.875f/3.5f)*hs[2][oxl] + (0.625f/3.5f)*hs[3][oxl]
          + (0.375f/3.5f)*hs[4][oxl] + (0.125f/3.5f)*hs[5][oxl];
    } else {                 // oy == 255, r0 == 958
      int j0 = 1018 - r0;
      acc = (0.125f/3.5f)*hs[j0+0][oxl] + (0.375f/3.5f)*hs[j0+1][oxl]
          + (0.625f/3.5f)*hs[j0+2][oxl] + (0.875f/3.5f)*hs[j0+3][oxl]
          + (0.875f/3.5f)*hs[j0+4][oxl] + (0.625f/3.5f)*hs[j0+5][oxl];
    }
    resz[((size_t)bc << 16) + ((size_t)oy << 8) + (size_t)(ox0 + oxl)] = acc;
  }
}

// ---------------- conv layer 0 (CI=3, CO=16, 256->128), LDS-staged, + f32 stats partials ----------------
__global__ void conv0_k(const float* __restrict__ in, const float* __restrict__ w,
                        const float* __restrict__ bias, float* __restrict__ out,
                        float* __restrict__ st0){
  __shared__ float tile[3][5][264];
  __shared__ float wsm[432];
  __shared__ float bs[16];
  __shared__ float sred[4][16][2];
  int t = blockIdx.x & 63;
  int b = blockIdx.x >> 6;
  for (int i = threadIdx.x; i < 432; i += 256) wsm[i] = w[i];
  if (threadIdx.x < 16) bs[threadIdx.x] = bias[threadIdx.x];
  const float* inb = in + (size_t)b*3*65536;
  int ih0 = 4*t - 1;
  for (int i = threadIdx.x; i < 3*5*258; i += 256){
    int ci  = i / (5*258);
    int rem = i % (5*258);
    int r   = rem / 258;
    int cc  = rem % 258;
    int ih  = ih0 + r;
    int iw  = cc - 1;
    float v = 0.f;
    if ((unsigned)ih < 256u && (unsigned)iw < 256u)
      v = inb[ci*65536 + ih*256 + iw];
    tile[ci][r][cc] = v;
  }
  __syncthreads();
  int lr = threadIdx.x >> 7;
  int ow = threadIdx.x & 127;
  float acc[16];
  #pragma unroll
  for (int j = 0; j < 16; j++) acc[j] = 0.f;
  #pragma unroll
  for (int ci = 0; ci < 3; ci++)
    #pragma unroll
    for (int kh = 0; kh < 3; kh++)
      #pragma unroll
      for (int kw = 0; kw < 3; kw++){
        float v = tile[ci][2*lr + kh][2*ow + kw];
        #pragma unroll
        for (int j = 0; j < 16; j++)
          acc[j] += v * wsm[j*27 + ci*9 + kh*3 + kw];
      }
  int s = t*256 + (int)threadIdx.x;
  size_t obase = (size_t)b*16*16384 + (size_t)s;
  float av[16];
  #pragma unroll
  for (int j = 0; j < 16; j++){
    float a = acc[j] + bs[j];
    a = (a >= 0.f) ? a : 0.2f*a;
    av[j] = a;
    out[obase + (size_t)j*16384] = a;
  }
  int wv = threadIdx.x >> 6;
  #pragma unroll
  for (int j = 0; j < 16; j++){
    float s1 = av[j], s2 = av[j]*av[j];
    #pragma unroll
    for (int o = 32; o > 0; o >>= 1){ s1 += __shfl_down(s1, o, 64); s2 += __shfl_down(s2, o, 64); }
    if ((threadIdx.x & 63) == 0){ sred[wv][j][0] = s1; sred[wv][j][1] = s2; }
  }
  __syncthreads();
  if (threadIdx.x < 16){
    float s1 = 0.f, s2 = 0.f;
    #pragma unroll
    for (int w2 = 0; w2 < 4; w2++){ s1 += sred[w2][threadIdx.x][0]; s2 += sred[w2][threadIdx.x][1]; }
    float* e = st0 + (((size_t)b*16 + threadIdx.x)*64 + t)*2;
    e[0] = s1; e[1] = s2;
  }
}

// ---------------- conv 3x3 stride2 pad1 + bias + leaky, fused inorm, chunk-4 batched loads ----------------
template<int CI, int CO, int IN, int OUT, int COB, int SPLIT, int TIN, int TOUT>
__global__ void __launch_bounds__(256, 1)
conv_leaky_k(const float* __restrict__ in, const float* __restrict__ w,
             const float* __restrict__ bias, float* __restrict__ out,
             const float* __restrict__ st_in, const float* __restrict__ g,
             const float* __restrict__ be, float* __restrict__ st_out){
  constexpr int P     = 256 / SPLIT;
  constexpr int TILES = (OUT*OUT + P - 1) / P;
  constexpr int CIS   = CI / SPLIT;
  constexpr int SUBS  = (TIN > 0) ? ((256/CI < TIN) ? 256/CI : TIN) : 1;
  int blk  = blockIdx.x;
  int b    = blk & 7;
  int rest = blk >> 3;
  int tile = rest % TILES;
  int cob  = rest / TILES;
  int co0  = cob * COB;
  __shared__ float ws[COB * CI * 9];
  __shared__ float bs[COB];
  __shared__ float red[(SPLIT > 1) ? 256 * COB : 1];
  __shared__ float sc[(TIN > 0) ? CI : 1];
  __shared__ float sh[(TIN > 0) ? CI : 1];
  __shared__ float pre[(TIN > 0) ? CI : 1][SUBS][2];
  for (int i = threadIdx.x; i < COB*CI*9; i += 256) ws[i] = w[(size_t)co0*CI*9 + i];
  if (threadIdx.x < COB) bs[threadIdx.x] = bias[co0 + threadIdx.x];
  if constexpr (TIN > 0){
    int c = threadIdx.x / SUBS, sub = threadIdx.x % SUBS;
    if (c < CI){
      const float* e = st_in + ((size_t)b*CI + c)*TIN*2;
      float s1 = 0.f, s2 = 0.f;
      for (int t2 = sub; t2 < TIN; t2 += SUBS){ s1 += e[t2*2]; s2 += e[t2*2+1]; }
      pre[c][sub][0] = s1; pre[c][sub][1] = s2;
    }
  }
  __syncthreads();
  if constexpr (TIN > 0){
    if (threadIdx.x < CI){
      float s1 = 0.f, s2 = 0.f;
      #pragma unroll
      for (int t2 = 0; t2 < SUBS; t2++){ s1 += pre[threadIdx.x][t2][0]; s2 += pre[threadIdx.x][t2][1]; }
      constexpr float hw = (float)(IN*IN);
      float mean = s1 * (1.f/hw);
      float var  = s2 * (1.f/hw) - mean*mean;
      float rstd = 1.f / sqrtf(var + 1e-5f);
      float scv  = g[threadIdx.x] * rstd;
      sc[threadIdx.x] = scv;
      sh[threadIdx.x] = be[threadIdx.x] - mean*scv;
    }
  }
  __syncthreads();
  int pix = threadIdx.x % P;
  int sp  = threadIdx.x / P;
  int s   = tile*P + pix;
  int oh = s / OUT, ow = s % OUT;
  float acc[COB];
  #pragma unroll
  for (int j = 0; j < COB; j++) acc[j] = 0.f;
  const float* inb = in + ((size_t)b*CI + sp*CIS) * (IN*IN);
  #pragma unroll
  for (int c0 = 0; c0 < CIS; c0 += 4){
    constexpr int CH = (CIS < 4) ? CIS : 4;
    #pragma unroll
    for (int kh = 0; kh < 3; kh++){
      int ih = oh*2 - 1 + kh;
      if ((unsigned)ih >= (unsigned)IN) continue;
      #pragma unroll
      for (int kw = 0; kw < 3; kw++){
        int iw = ow*2 - 1 + kw;
        if ((unsigned)iw >= (unsigned)IN) continue;
        const float* p0 = inb + (size_t)c0*(IN*IN) + ih*IN + iw;
        float vv[CH];
        #pragma unroll
        for (int ci = 0; ci < CH; ci++) vv[ci] = p0[(size_t)ci*(IN*IN)];
        if constexpr (TIN > 0){
          #pragma unroll
          for (int ci = 0; ci < CH; ci++) vv[ci] = vv[ci]*sc[sp*CIS+c0+ci] + sh[sp*CIS+c0+ci];
        }
        #pragma unroll
        for (int ci = 0; ci < CH; ci++){
          #pragma unroll
          for (int j = 0; j < COB; j++)
            acc[j] += vv[ci] * ws[j*CI*9 + (sp*CIS+c0+ci)*9 + kh*3 + kw];
        }
      }
    }
  }
  if constexpr (SPLIT > 1){
    #pragma unroll
    for (int j = 0; j < COB; j++) red[threadIdx.x*COB + j] = acc[j];
    __syncthreads();
    if (sp == 0){
      #pragma unroll
      for (int s2 = 1; s2 < SPLIT; s2++)
        #pragma unroll
        for (int j = 0; j < COB; j++)
          acc[j] += red[(pix + s2*P)*COB + j];
    }
  }
  float av[COB];
  if (sp == 0){
    size_t obase = ((size_t)b*CO + co0) * (size_t)(OUT*OUT) + s;
    #pragma unroll
    for (int j = 0; j < COB; j++){
      float a = acc[j] + bs[j];
      a = (a >= 0.f) ? a : 0.2f*a;
      av[j] = a;
      out[obase + (size_t)j*OUT*OUT] = a;
    }
  }
  if constexpr (TOUT > 0){
    constexpr int NW = P / 64;
    __shared__ float sred2[NW][COB][2];
    if (threadIdx.x < P){
      #pragma unroll
      for (int j = 0; j < COB; j++){
        float s1 = av[j], s2 = av[j]*av[j];
        #pragma unroll
        for (int o = 32; o > 0; o >>= 1){ s1 += __shfl_down(s1, o, 64); s2 += __shfl_down(s2, o, 64); }
        if ((threadIdx.x & 63) == 0){ int wv = threadIdx.x >> 6; sred2[wv][j][0] = s1; sred2[wv][j][1] = s2; }
      }
    }
    __syncthreads();
    if (threadIdx.x < COB){
      float s1 = 0.f, s2 = 0.f;
      #pragma unroll
      for (int wv = 0; wv < NW; wv++){ s1 += sred2[wv][threadIdx.x][0]; s2 += sred2[wv][threadIdx.x][1]; }
      float* e = st_out + (((size_t)b*CO + co0 + threadIdx.x)*TOUT + tile)*2;
      e[0] = s1; e[1] = s2;
    }
  }
}

// ---------------- conv4 + fused gemv partials ----------------
__global__ void __launch_bounds__(256, 1)
conv4_gemv_k(const float* __restrict__ in, const float* __restrict__ w,
             const float* __restrict__ bias, const float* __restrict__ st_in,
             const float* __restrict__ g, const float* __restrict__ be,
             const float* __restrict__ wgw, float* __restrict__ part){
  __shared__ float ws[4*128*9];
  __shared__ float bs[4];
  __shared__ float red[256*4];
  __shared__ float sc[128], sh[128];
  __shared__ float pre[128][2][2];
  int blk = blockIdx.x;
  int b   = blk & 7;
  int cob = blk >> 3;            // 0..31
  int co0 = cob * 4;
  for (int i = threadIdx.x; i < 4*128*9; i += 256) ws[i] = w[(size_t)co0*128*9 + i];
  if (threadIdx.x < 4) bs[threadIdx.x] = bias[co0 + threadIdx.x];
  {
    int c = threadIdx.x >> 1, sub = threadIdx.x & 1;
    if (c < 128){
      const float* e = st_in + ((size_t)b*128 + c)*2*2;
      pre[c][sub][0] = e[sub*2]; pre[c][sub][1] = e[sub*2+1];
    }
  }
  __syncthreads();
  if (threadIdx.x < 128){
    float s1 = pre[threadIdx.x][0][0] + pre[threadIdx.x][1][0];
    float s2 = pre[threadIdx.x][0][1] + pre[threadIdx.x][1][1];
    float mean = s1 * (1.f/256.f);
    float var  = s2 * (1.f/256.f) - mean*mean;
    float rstd = 1.f / sqrtf(var + 1e-5f);
    float scv  = g[threadIdx.x] * rstd;
    sc[threadIdx.x] = scv;
    sh[threadIdx.x] = be[threadIdx.x] - mean*scv;
  }
  __syncthreads();
  int pix = threadIdx.x & 63;
  int sp  = threadIdx.x >> 6;
  int s   = pix;
  int oh = s >> 3, ow = s & 7;
  float acc[4];
  #pragma unroll
  for (int j = 0; j < 4; j++) acc[j] = 0.f;
  const float* inb = in + ((size_t)b*128 + sp*32) * 256;
  #pragma unroll
  for (int c0 = 0; c0 < 32; c0 += 4){
    #pragma unroll
    for (int kh = 0; kh < 3; kh++){
      int ih = oh*2 - 1 + kh;
      if ((unsigned)ih >= 16u) continue;
      #pragma unroll
      for (int kw = 0; kw < 3; kw++){
        int iw = ow*2 - 1 + kw;
        if ((unsigned)iw >= 16u) continue;
        const float* p0 = inb + (size_t)c0*256 + ih*16 + iw;
        float vv[4];
        #pragma unroll
        for (int ci = 0; ci < 4; ci++) vv[ci] = p0[ci*256];
        #pragma unroll
        for (int ci = 0; ci < 4; ci++) vv[ci] = vv[ci]*sc[sp*32+c0+ci] + sh[sp*32+c0+ci];
        #pragma unroll
        for (int ci = 0; ci < 4; ci++){
          #pragma unroll
          for (int j = 0; j < 4; j++)
            acc[j] += vv[ci] * ws[j*128*9 + (sp*32+c0+ci)*9 + kh*3 + kw];
        }
      }
    }
  }
  #pragma unroll
  for (int j = 0; j < 4; j++) red[threadIdx.x*4 + j] = acc[j];
  __syncthreads();
  if (sp == 0){
    #pragma unroll
    for (int s2 = 1; s2 < 4; s2++)
      #pragma unroll
      for (int j = 0; j < 4; j++)
        acc[j] += red[(pix + s2*64)*4 + j];
    float av[4];
    #pragma unroll
    for (int j = 0; j < 4; j++){
      float a = acc[j] + bs[j];
      av[j] = (a >= 0.f) ? a : 0.2f*a;
    }
    float p3[3];
    #pragma unroll
    for (int o = 0; o < 3; o++){
      float t = 0.f;
      #pragma unroll
      for (int j = 0; j < 4; j++)
        t += av[j] * wgw[(size_t)o*8192 + (size_t)(co0+j)*64 + s];
      #pragma unroll
      for (int off = 32; off > 0; off >>= 1) t += __shfl_down(t, off, 64);
      p3[o] = t;
    }
    if (pix == 0){
      float* e = part + ((size_t)b*32 + cob)*3;
      e[0] = p3[0]; e[1] = p3[1]; e[2] = p3[2];
    }
  }
}

// ---------------- luts: finish gemv (reduce partials) + weights@lut_w.T + bf16 u16 table ----------------
__global__ void luts_k(const float* __restrict__ part, const float* __restrict__ wgb,
                       const float* __restrict__ lut_w, const float* __restrict__ verts,
                       U16* __restrict__ lp16, float* __restrict__ outp){
  __shared__ float wf_s[24];
  if (threadIdx.x < 24){
    int b = threadIdx.x / 3, o = threadIdx.x % 3;
    float s = 0.f;
    for (int cob = 0; cob < 32; cob++) s += part[((size_t)b*32 + cob)*3 + o];
    s += wgb[o];
    wf_s[threadIdx.x] = s;
    if (blockIdx.x == 0) outp[25165824 + threadIdx.x] = s;
  }
  __syncthreads();
  if (blockIdx.x == 0 && threadIdx.x < 99) outp[26028336 + threadIdx.x] = verts[threadIdx.x];
  int j = blockIdx.x * 256 + threadIdx.x;
  if (j >= 107811) return;
  float l0 = lut_w[3*j+0], l1 = lut_w[3*j+1], l2 = lut_w[3*j+2];
  int c = j / 35937;
  int i = j - c * 35937;
  #pragma unroll
  for (int b = 0; b < 8; b++){
    float w0 = wf_s[b*3+0], w1 = wf_s[b*3+1], w2 = wf_s[b*3+2];
    float v  = w0*l0 + w1*l1 + w2*l2;
    outp[25165848 + (size_t)b*107811 + j] = v;
    lp16[(size_t)(b*3 + c)*35940 + i] = (U16)f2bf_rne(v);
  }
}

// ---------------- apply: trilinear LUT, non-redundant bf16 u16 table (71.9 KB -> 2 blocks/CU) ----------------
// Corner pair (l[s], l[s+1]) reconstructed from aligned b32 words:
//   A = W[s>>1], B = W[(s+1)>>1]; pair = (s&1) ? (A>>16)|(B<<16) : A
// -> b32-only LDS reads (8/pixel), bit-identical interpolation values.
static __device__ __forceinline__ U32 mkpair(const U32* W, int s){
  U32 A = W[s >> 1];
  U32 B = W[(s + 1) >> 1];
  return (s & 1) ? ((A >> 16) | (B << 16)) : A;
}

static __device__ __forceinline__ void apply_phase(const U32* W, const float4* rv,
                                                   const float4* gv, const float4* bv,
                                                   float* ob, int base){
  #pragma unroll
  for (int k = 0; k < 4; k++){
    float rr[4] = {rv[k].x, rv[k].y, rv[k].z, rv[k].w};
    float gg[4] = {gv[k].x, gv[k].y, gv[k].z, gv[k].w};
    float bb[4] = {bv[k].x, bv[k].y, bv[k].z, bv[k].w};
    U32 pw[4][4];
    float w00[4], w01[4], w10[4], w11[4], drx[4];
    #pragma unroll
    for (int h = 0; h < 4; h++){
      float rq = rr[h] * 32.f;
      float gq = gg[h] * 32.f;
      float bq = bb[h] * 32.f;
      int ir = (int)rq; ir = ir > 31 ? 31 : ir;
      int ig = (int)gq; ig = ig > 31 ? 31 : ig;
      int ib = (int)bq; ib = ib > 31 ? 31 : ib;
      float dr = rq - (float)ir;
      float dg = gq - (float)ig;
      float db = bq - (float)ib;
      int lin = (ib*33 + ig)*33 + ir;
      pw[h][0] = mkpair(W, lin);
      pw[h][1] = mkpair(W, lin + 33);
      pw[h][2] = mkpair(W, lin + 1089);
      pw[h][3] = mkpair(W, lin + 1122);
      float t = db*dg;
      w11[h] = t;
      w10[h] = db - t;
      w01[h] = dg - t;
      w00[h] = 1.f - db - dg + t;
      drx[h] = dr;
    }
    float res[4];
    #pragma unroll
    for (int h = 0; h < 4; h++){
      float odr = 1.f - drx[h];
      float v0 = odr*bflo2f(pw[h][0]) + drx[h]*bfhi2f(pw[h][0]);
      float v1 = odr*bflo2f(pw[h][1]) + drx[h]*bfhi2f(pw[h][1]);
      float v2 = odr*bflo2f(pw[h][2]) + drx[h]*bfhi2f(pw[h][2]);
      float v3 = odr*bflo2f(pw[h][3]) + drx[h]*bfhi2f(pw[h][3]);
      res[h] = w00[h]*v0 + w01[h]*v1 + w10[h]*v2 + w11[h]*v3;
    }
    *(float4*)(ob + base + k*4096) = make_float4(res[0], res[1], res[2], res[3]);
  }
}

__global__ void __launch_bounds__(1024, 8) ailut_apply_k(const float* __restrict__ x,
                                                         const U16* __restrict__ lp16,
                                                         float* __restrict__ outp){
  __shared__ U16 ls16[35952];           // 71904 B -> 2 blocks (32 waves) per CU
  int b = blockIdx.z, c = blockIdx.y;
  const size_t plane = 1048576;
  const float* xb = x + (size_t)b*3*plane;
  int base = blockIdx.x * 32768 + (int)threadIdx.x*4;
  float4 rv[4], gv[4], bv[4];
  #pragma unroll
  for (int k = 0; k < 4; k++){
    int p0 = base + k*4096;
    rv[k] = *(const float4*)(xb + p0);
    gv[k] = *(const float4*)(xb + plane + p0);
    bv[k] = *(const float4*)(xb + 2*plane + p0);
  }
  const U16* lsrc = lp16 + (size_t)(b*3 + c)*35940;
  for (int i = threadIdx.x; i < 4493; i += 1024)    // 4493*16B = 71888 B >= 35938 u16
    __builtin_amdgcn_global_load_lds(
        (const __attribute__((address_space(1))) void*)(lsrc + 8*(size_t)i),
        (__attribute__((address_space(3))) void*)(ls16 + 8*i), 16, 0, 0);
  __syncthreads();
  const U32* W = (const U32*)ls16;
  float* ob = outp + ((size_t)b*3 + c)*plane;
  apply_phase(W, rv, gv, bv, ob, base);
  #pragma unroll
  for (int k = 0; k < 4; k++){
    int p0 = base + 16384 + k*4096;
    rv[k] = *(const float4*)(xb + p0);
    gv[k] = *(const float4*)(xb + plane + p0);
    bv[k] = *(const float4*)(xb + 2*plane + p0);
  }
  apply_phase(W, rv, gv, bv, ob, base + 16384);
}

extern "C" void kernel_launch(void* const* d_in, const int* in_sizes, int n_in,
                              void* d_out, int out_size, void* d_ws, size_t ws_size,
                              hipStream_t stream){
  const float* x    = (const float*)d_in[0];
  const float* cw0  = (const float*)d_in[1];
  const float* cb0  = (const float*)d_in[2];
  const float* cw1  = (const float*)d_in[3];
  const float* cb1  = (const float*)d_in[4];
  const float* cw2  = (const float*)d_in[5];
  const float* cb2  = (const float*)d_in[6];
  const float* cw3  = (const float*)d_in[7];
  const float* cb3  = (const float*)d_in[8];
  const float* cw4  = (const float*)d_in[9];
  const float* cb4  = (const float*)d_in[10];
  const float* g0   = (const float*)d_in[11];
  const float* be0  = (const float*)d_in[12];
  const float* g1   = (const float*)d_in[13];
  const float* be1  = (const float*)d_in[14];
  const float* g2   = (const float*)d_in[15];
  const float* be2  = (const float*)d_in[16];
  const float* g3   = (const float*)d_in[17];
  const float* be3  = (const float*)d_in[18];
  const float* wgw  = (const float*)d_in[19];
  const float* wgb  = (const float*)d_in[20];
  const float* lutw = (const float*)d_in[21];
  const float* vert = (const float*)d_in[22];
  float* out = (float*)d_out;
  float* ws  = (float*)d_ws;

  // ws layout (floats): lp16[24*35940+pad u16 = 431,344 B] | st0..st3 | resz | acts
  U16*   lp16 = (U16*)ws;
  float* st0  = ws + 862720;            // 8*16*64*2  = 16384
  float* st1  = ws + 879104;            // 8*32*16*2  = 8192
  float* st2  = ws + 887296;            // 8*64*4*2   = 4096
  float* st3  = ws + 891392;            // 8*128*2*2  = 4096
  float* resz = ws + 895488;            // 1572864
  float* act0 = ws + 2468352;           // 2097152
  float* act1 = act0 + 2097152;         // 1048576
  float* act2 = act1 + 1048576;         // 524288
  float* act3 = act2 + 524288;          // 262144
  float* part = act3 + 262144;          // 768

  resize_k<<<1536, 256, 0, stream>>>(x, resz);

  conv0_k<<<512, 256, 0, stream>>>(resz, cw0, cb0, act0, st0);
  conv_leaky_k<16,32,128,64,8,1,64,16>
      <<<8*4*16, 256, 0, stream>>>(act0, cw1, cb1, act1, st0, g0, be0, st1);
  conv_leaky_k<32,64,64,32,4,1,16,4>
      <<<8*16*4, 256, 0, stream>>>(act1, cw2, cb2, act2, st1, g1, be1, st2);
  conv_leaky_k<64,128,32,16,4,2,4,2>
      <<<8*32*2, 256, 0, stream>>>(act2, cw3, cb3, act3, st2, g2, be2, st3);
  conv4_gemv_k<<<256, 256, 0, stream>>>(act3, cw4, cb4, st3, g3, be3, wgw, part);

  luts_k<<<422, 256, 0, stream>>>(part, wgb, lutw, vert, lp16, out);
  ailut_apply_k<<<dim3(32,3,8), 1024, 0, stream>>>(x, lp16, out);
}

// Round 14
// 182.081 us; speedup vs baseline: 1.2020x; 1.2020x over previous
//
#include <hip/hip_runtime.h>
#include <hip/hip_bf16.h>
#include <stdint.h>

typedef unsigned int U32;

static __device__ __forceinline__ U32 f2bf_rne(float f){
  U32 u; __builtin_memcpy(&u, &f, 4);
  u = (u + 0x7fffu + ((u >> 16) & 1u)) >> 16;
  return u & 0xffffu;
}
static __device__ __forceinline__ float bflo2f(U32 p){
  U32 u = p << 16; float f; __builtin_memcpy(&f, &u, 4); return f;
}
static __device__ __forceinline__ float bfhi2f(U32 p){
  U32 u = p & 0xffff0000u; float f; __builtin_memcpy(&f, &u, 4); return f;
}

// ---------------- fused resize: 4x antialiased bilinear, H then V, one kernel ----------------
__global__ void resize_k(const float* __restrict__ x, float* __restrict__ resz){
  __shared__ float hs[68][64];
  int blk = blockIdx.x;
  int tx = blk & 3;
  int ty = (blk >> 2) & 15;
  int bc = blk >> 6;
  int ox0 = tx << 6, oy0 = ty << 4;
  int r0 = 4*oy0 - 2; if (r0 < 0) r0 = 0;
  if (r0 > 956) r0 = 958;              // last tile: rows 958..1023 (66 used)
  const float* src = x + ((size_t)bc << 20);
  #pragma unroll 4
  for (int i = threadIdx.x; i < 68*64; i += 256){
    int r   = i >> 6;
    int oxl = i & 63;
    int ox  = ox0 + oxl;
    int rr  = r0 + r; if (rr > 1023) rr = 1023;
    const float2* row2 = (const float2*)(src + ((size_t)rr << 10));
    float acc;
    if (ox >= 1 && ox <= 254){
      float2 a = row2[2*ox-1];
      float2 b = row2[2*ox];
      float2 c = row2[2*ox+1];
      float2 d = row2[2*ox+2];
      acc = (1.f/32)*(a.x + d.y)
          + (3.f/32)*(a.y + d.x)
          + (5.f/32)*(b.x + c.y)
          + (7.f/32)*(b.y + c.x);
    } else if (ox == 0){
      float2 a = row2[0], b = row2[1], c = row2[2];
      acc = (0.625f/3.5f)*a.x + (0.875f/3.5f)*a.y
          + (0.875f/3.5f)*b.x + (0.625f/3.5f)*b.y
          + (0.375f/3.5f)*c.x + (0.125f/3.5f)*c.y;
    } else {
      float2 a = row2[509], b = row2[510], c = row2[511];
      acc = (0.125f/3.5f)*a.x + (0.375f/3.5f)*a.y
          + (0.625f/3.5f)*b.x + (0.875f/3.5f)*b.y
          + (0.875f/3.5f)*c.x + (0.625f/3.5f)*c.y;
    }
    hs[r][oxl] = acc;
  }
  __syncthreads();
  for (int i = threadIdx.x; i < 16*64; i += 256){
    int oyl = i >> 6, oxl = i & 63;
    int oy = oy0 + oyl;
    float acc;
    if (oy >= 1 && oy <= 254){
      int j0 = 4*oy - 2 - r0;
      acc = (1.f/32)*(hs[j0+0][oxl] + hs[j0+7][oxl])
          + (3.f/32)*(hs[j0+1][oxl] + hs[j0+6][oxl])
          + (5.f/32)*(hs[j0+2][oxl] + hs[j0+5][oxl])
          + (7.f/32)*(hs[j0+3][oxl] + hs[j0+4][oxl]);
    } else if (oy == 0){     // r0 == 0
      acc = (0.625f/3.5f)*hs[0][oxl] + (0.875f/3.5f)*hs[1][oxl]
          + (0.875f/3.5f)*hs[2][oxl] + (0.625f/3.5f)*hs[3][oxl]
          + (0.375f/3.5f)*hs[4][oxl] + (0.125f/3.5f)*hs[5][oxl];
    } else {                 // oy == 255, r0 == 958
      int j0 = 1018 - r0;
      acc = (0.125f/3.5f)*hs[j0+0][oxl] + (0.375f/3.5f)*hs[j0+1][oxl]
          + (0.625f/3.5f)*hs[j0+2][oxl] + (0.875f/3.5f)*hs[j0+3][oxl]
          + (0.875f/3.5f)*hs[j0+4][oxl] + (0.625f/3.5f)*hs[j0+5][oxl];
    }
    resz[((size_t)bc << 16) + ((size_t)oy << 8) + (size_t)(ox0 + oxl)] = acc;
  }
}

// ---------------- conv layer 0 (CI=3, CO=16, 256->128), LDS-staged, + f32 stats partials ----------------
__global__ void conv0_k(const float* __restrict__ in, const float* __restrict__ w,
                        const float* __restrict__ bias, float* __restrict__ out,
                        float* __restrict__ st0){
  __shared__ float tile[3][5][264];
  __shared__ float wsm[432];
  __shared__ float bs[16];
  __shared__ float sred[4][16][2];
  int t = blockIdx.x & 63;
  int b = blockIdx.x >> 6;
  for (int i = threadIdx.x; i < 432; i += 256) wsm[i] = w[i];
  if (threadIdx.x < 16) bs[threadIdx.x] = bias[threadIdx.x];
  const float* inb = in + (size_t)b*3*65536;
  int ih0 = 4*t - 1;
  for (int i = threadIdx.x; i < 3*5*258; i += 256){
    int ci  = i / (5*258);
    int rem = i % (5*258);
    int r   = rem / 258;
    int cc  = rem % 258;
    int ih  = ih0 + r;
    int iw  = cc - 1;
    float v = 0.f;
    if ((unsigned)ih < 256u && (unsigned)iw < 256u)
      v = inb[ci*65536 + ih*256 + iw];
    tile[ci][r][cc] = v;
  }
  __syncthreads();
  int lr = threadIdx.x >> 7;
  int ow = threadIdx.x & 127;
  float acc[16];
  #pragma unroll
  for (int j = 0; j < 16; j++) acc[j] = 0.f;
  #pragma unroll
  for (int ci = 0; ci < 3; ci++)
    #pragma unroll
    for (int kh = 0; kh < 3; kh++)
      #pragma unroll
      for (int kw = 0; kw < 3; kw++){
        float v = tile[ci][2*lr + kh][2*ow + kw];
        #pragma unroll
        for (int j = 0; j < 16; j++)
          acc[j] += v * wsm[j*27 + ci*9 + kh*3 + kw];
      }
  int s = t*256 + (int)threadIdx.x;
  size_t obase = (size_t)b*16*16384 + (size_t)s;
  float av[16];
  #pragma unroll
  for (int j = 0; j < 16; j++){
    float a = acc[j] + bs[j];
    a = (a >= 0.f) ? a : 0.2f*a;
    av[j] = a;
    out[obase + (size_t)j*16384] = a;
  }
  int wv = threadIdx.x >> 6;
  #pragma unroll
  for (int j = 0; j < 16; j++){
    float s1 = av[j], s2 = av[j]*av[j];
    #pragma unroll
    for (int o = 32; o > 0; o >>= 1){ s1 += __shfl_down(s1, o, 64); s2 += __shfl_down(s2, o, 64); }
    if ((threadIdx.x & 63) == 0){ sred[wv][j][0] = s1; sred[wv][j][1] = s2; }
  }
  __syncthreads();
  if (threadIdx.x < 16){
    float s1 = 0.f, s2 = 0.f;
    #pragma unroll
    for (int w2 = 0; w2 < 4; w2++){ s1 += sred[w2][threadIdx.x][0]; s2 += sred[w2][threadIdx.x][1]; }
    float* e = st0 + (((size_t)b*16 + threadIdx.x)*64 + t)*2;
    e[0] = s1; e[1] = s2;
  }
}

// ---------------- conv 3x3 stride2 pad1 + bias + leaky, fused inorm, chunk-4 batched loads ----------------
template<int CI, int CO, int IN, int OUT, int COB, int SPLIT, int TIN, int TOUT>
__global__ void __launch_bounds__(256, 1)
conv_leaky_k(const float* __restrict__ in, const float* __restrict__ w,
             const float* __restrict__ bias, float* __restrict__ out,
             const float* __restrict__ st_in, const float* __restrict__ g,
             const float* __restrict__ be, float* __restrict__ st_out){
  constexpr int P     = 256 / SPLIT;
  constexpr int TILES = (OUT*OUT + P - 1) / P;
  constexpr int CIS   = CI / SPLIT;
  constexpr int SUBS  = (TIN > 0) ? ((256/CI < TIN) ? 256/CI : TIN) : 1;
  int blk  = blockIdx.x;
  int b    = blk & 7;
  int rest = blk >> 3;
  int tile = rest % TILES;
  int cob  = rest / TILES;
  int co0  = cob * COB;
  __shared__ float ws[COB * CI * 9];
  __shared__ float bs[COB];
  __shared__ float red[(SPLIT > 1) ? 256 * COB : 1];
  __shared__ float sc[(TIN > 0) ? CI : 1];
  __shared__ float sh[(TIN > 0) ? CI : 1];
  __shared__ float pre[(TIN > 0) ? CI : 1][SUBS][2];
  for (int i = threadIdx.x; i < COB*CI*9; i += 256) ws[i] = w[(size_t)co0*CI*9 + i];
  if (threadIdx.x < COB) bs[threadIdx.x] = bias[co0 + threadIdx.x];
  if constexpr (TIN > 0){
    int c = threadIdx.x / SUBS, sub = threadIdx.x % SUBS;
    if (c < CI){
      const float* e = st_in + ((size_t)b*CI + c)*TIN*2;
      float s1 = 0.f, s2 = 0.f;
      for (int t2 = sub; t2 < TIN; t2 += SUBS){ s1 += e[t2*2]; s2 += e[t2*2+1]; }
      pre[c][sub][0] = s1; pre[c][sub][1] = s2;
    }
  }
  __syncthreads();
  if constexpr (TIN > 0){
    if (threadIdx.x < CI){
      float s1 = 0.f, s2 = 0.f;
      #pragma unroll
      for (int t2 = 0; t2 < SUBS; t2++){ s1 += pre[threadIdx.x][t2][0]; s2 += pre[threadIdx.x][t2][1]; }
      constexpr float hw = (float)(IN*IN);
      float mean = s1 * (1.f/hw);
      float var  = s2 * (1.f/hw) - mean*mean;
      float rstd = 1.f / sqrtf(var + 1e-5f);
      float scv  = g[threadIdx.x] * rstd;
      sc[threadIdx.x] = scv;
      sh[threadIdx.x] = be[threadIdx.x] - mean*scv;
    }
  }
  __syncthreads();
  int pix = threadIdx.x % P;
  int sp  = threadIdx.x / P;
  int s   = tile*P + pix;
  int oh = s / OUT, ow = s % OUT;
  float acc[COB];
  #pragma unroll
  for (int j = 0; j < COB; j++) acc[j] = 0.f;
  const float* inb = in + ((size_t)b*CI + sp*CIS) * (IN*IN);
  #pragma unroll
  for (int c0 = 0; c0 < CIS; c0 += 4){
    constexpr int CH = (CIS < 4) ? CIS : 4;
    #pragma unroll
    for (int kh = 0; kh < 3; kh++){
      int ih = oh*2 - 1 + kh;
      if ((unsigned)ih >= (unsigned)IN) continue;
      #pragma unroll
      for (int kw = 0; kw < 3; kw++){
        int iw = ow*2 - 1 + kw;
        if ((unsigned)iw >= (unsigned)IN) continue;
        const float* p0 = inb + (size_t)c0*(IN*IN) + ih*IN + iw;
        float vv[CH];
        #pragma unroll
        for (int ci = 0; ci < CH; ci++) vv[ci] = p0[(size_t)ci*(IN*IN)];
        if constexpr (TIN > 0){
          #pragma unroll
          for (int ci = 0; ci < CH; ci++) vv[ci] = vv[ci]*sc[sp*CIS+c0+ci] + sh[sp*CIS+c0+ci];
        }
        #pragma unroll
        for (int ci = 0; ci < CH; ci++){
          #pragma unroll
          for (int j = 0; j < COB; j++)
            acc[j] += vv[ci] * ws[j*CI*9 + (sp*CIS+c0+ci)*9 + kh*3 + kw];
        }
      }
    }
  }
  if constexpr (SPLIT > 1){
    #pragma unroll
    for (int j = 0; j < COB; j++) red[threadIdx.x*COB + j] = acc[j];
    __syncthreads();
    if (sp == 0){
      #pragma unroll
      for (int s2 = 1; s2 < SPLIT; s2++)
        #pragma unroll
        for (int j = 0; j < COB; j++)
          acc[j] += red[(pix + s2*P)*COB + j];
    }
  }
  float av[COB];
  if (sp == 0){
    size_t obase = ((size_t)b*CO + co0) * (size_t)(OUT*OUT) + s;
    #pragma unroll
    for (int j = 0; j < COB; j++){
      float a = acc[j] + bs[j];
      a = (a >= 0.f) ? a : 0.2f*a;
      av[j] = a;
      out[obase + (size_t)j*OUT*OUT] = a;
    }
  }
  if constexpr (TOUT > 0){
    constexpr int NW = P / 64;
    __shared__ float sred2[NW][COB][2];
    if (threadIdx.x < P){
      #pragma unroll
      for (int j = 0; j < COB; j++){
        float s1 = av[j], s2 = av[j]*av[j];
        #pragma unroll
        for (int o = 32; o > 0; o >>= 1){ s1 += __shfl_down(s1, o, 64); s2 += __shfl_down(s2, o, 64); }
        if ((threadIdx.x & 63) == 0){ int wv = threadIdx.x >> 6; sred2[wv][j][0] = s1; sred2[wv][j][1] = s2; }
      }
    }
    __syncthreads();
    if (threadIdx.x < COB){
      float s1 = 0.f, s2 = 0.f;
      #pragma unroll
      for (int wv = 0; wv < NW; wv++){ s1 += sred2[wv][threadIdx.x][0]; s2 += sred2[wv][threadIdx.x][1]; }
      float* e = st_out + (((size_t)b*CO + co0 + threadIdx.x)*TOUT + tile)*2;
      e[0] = s1; e[1] = s2;
    }
  }
}

// ---------------- conv4 + fused gemv partials ----------------
__global__ void __launch_bounds__(256, 1)
conv4_gemv_k(const float* __restrict__ in, const float* __restrict__ w,
             const float* __restrict__ bias, const float* __restrict__ st_in,
             const float* __restrict__ g, const float* __restrict__ be,
             const float* __restrict__ wgw, float* __restrict__ part){
  __shared__ float ws[4*128*9];
  __shared__ float bs[4];
  __shared__ float red[256*4];
  __shared__ float sc[128], sh[128];
  __shared__ float pre[128][2][2];
  int blk = blockIdx.x;
  int b   = blk & 7;
  int cob = blk >> 3;            // 0..31
  int co0 = cob * 4;
  for (int i = threadIdx.x; i < 4*128*9; i += 256) ws[i] = w[(size_t)co0*128*9 + i];
  if (threadIdx.x < 4) bs[threadIdx.x] = bias[co0 + threadIdx.x];
  {
    int c = threadIdx.x >> 1, sub = threadIdx.x & 1;
    if (c < 128){
      const float* e = st_in + ((size_t)b*128 + c)*2*2;
      pre[c][sub][0] = e[sub*2]; pre[c][sub][1] = e[sub*2+1];
    }
  }
  __syncthreads();
  if (threadIdx.x < 128){
    float s1 = pre[threadIdx.x][0][0] + pre[threadIdx.x][1][0];
    float s2 = pre[threadIdx.x][0][1] + pre[threadIdx.x][1][1];
    float mean = s1 * (1.f/256.f);
    float var  = s2 * (1.f/256.f) - mean*mean;
    float rstd = 1.f / sqrtf(var + 1e-5f);
    float scv  = g[threadIdx.x] * rstd;
    sc[threadIdx.x] = scv;
    sh[threadIdx.x] = be[threadIdx.x] - mean*scv;
  }
  __syncthreads();
  int pix = threadIdx.x & 63;
  int sp  = threadIdx.x >> 6;
  int s   = pix;
  int oh = s >> 3, ow = s & 7;
  float acc[4];
  #pragma unroll
  for (int j = 0; j < 4; j++) acc[j] = 0.f;
  const float* inb = in + ((size_t)b*128 + sp*32) * 256;
  #pragma unroll
  for (int c0 = 0; c0 < 32; c0 += 4){
    #pragma unroll
    for (int kh = 0; kh < 3; kh++){
      int ih = oh*2 - 1 + kh;
      if ((unsigned)ih >= 16u) continue;
      #pragma unroll
      for (int kw = 0; kw < 3; kw++){
        int iw = ow*2 - 1 + kw;
        if ((unsigned)iw >= 16u) continue;
        const float* p0 = inb + (size_t)c0*256 + ih*16 + iw;
        float vv[4];
        #pragma unroll
        for (int ci = 0; ci < 4; ci++) vv[ci] = p0[ci*256];
        #pragma unroll
        for (int ci = 0; ci < 4; ci++) vv[ci] = vv[ci]*sc[sp*32+c0+ci] + sh[sp*32+c0+ci];
        #pragma unroll
        for (int ci = 0; ci < 4; ci++){
          #pragma unroll
          for (int j = 0; j < 4; j++)
            acc[j] += vv[ci] * ws[j*128*9 + (sp*32+c0+ci)*9 + kh*3 + kw];
        }
      }
    }
  }
  #pragma unroll
  for (int j = 0; j < 4; j++) red[threadIdx.x*4 + j] = acc[j];
  __syncthreads();
  if (sp == 0){
    #pragma unroll
    for (int s2 = 1; s2 < 4; s2++)
      #pragma unroll
      for (int j = 0; j < 4; j++)
        acc[j] += red[(pix + s2*64)*4 + j];
    float av[4];
    #pragma unroll
    for (int j = 0; j < 4; j++){
      float a = acc[j] + bs[j];
      av[j] = (a >= 0.f) ? a : 0.2f*a;
    }
    float p3[3];
    #pragma unroll
    for (int o = 0; o < 3; o++){
      float t = 0.f;
      #pragma unroll
      for (int j = 0; j < 4; j++)
        t += av[j] * wgw[(size_t)o*8192 + (size_t)(co0+j)*64 + s];
      #pragma unroll
      for (int off = 32; off > 0; off >>= 1) t += __shfl_down(t, off, 64);
      p3[o] = t;
    }
    if (pix == 0){
      float* e = part + ((size_t)b*32 + cob)*3;
      e[0] = p3[0]; e[1] = p3[1]; e[2] = p3[2];
    }
  }
}

// ---------------- luts: finish gemv (reduce partials) + weights@lut_w.T + bf16 pair table ----------------
__global__ void luts_k(const float* __restrict__ part, const float* __restrict__ wgb,
                       const float* __restrict__ lut_w, const float* __restrict__ verts,
                       U32* __restrict__ lp, float* __restrict__ outp){
  __shared__ float wf_s[24];
  if (threadIdx.x < 24){
    int b = threadIdx.x / 3, o = threadIdx.x % 3;
    float s = 0.f;
    for (int cob = 0; cob < 32; cob++) s += part[((size_t)b*32 + cob)*3 + o];
    s += wgb[o];
    wf_s[threadIdx.x] = s;
    if (blockIdx.x == 0) outp[25165824 + threadIdx.x] = s;
  }
  __syncthreads();
  if (blockIdx.x == 0 && threadIdx.x < 99) outp[26028336 + threadIdx.x] = verts[threadIdx.x];
  int j = blockIdx.x * 256 + threadIdx.x;
  if (j >= 107811) return;
  int jn = (j + 1 < 107811) ? (j + 1) : j;
  float l0 = lut_w[3*j+0], l1 = lut_w[3*j+1], l2 = lut_w[3*j+2];
  float m0 = lut_w[3*jn+0], m1 = lut_w[3*jn+1], m2 = lut_w[3*jn+2];
  int c = j / 35937;
  int i = j - c * 35937;
  #pragma unroll
  for (int b = 0; b < 8; b++){
    float w0 = wf_s[b*3+0], w1 = wf_s[b*3+1], w2 = wf_s[b*3+2];
    float v  = w0*l0 + w1*l1 + w2*l2;
    float vn = w0*m0 + w1*m1 + w2*m2;
    outp[25165848 + (size_t)b*107811 + j] = v;
    lp[(size_t)(b*3 + c)*35940 + i] = f2bf_rne(v) | (f2bf_rne(vn) << 16);
  }
}

// ---------------- apply: trilinear LUT, one (b,c) LUT channel in LDS (u32 bf16-pair table) ----------------
static __device__ __forceinline__ void apply_phase(const U32* ls, const float4* rv,
                                                   const float4* gv, const float4* bv,
                                                   float* ob, int base){
  #pragma unroll
  for (int k = 0; k < 4; k++){
    float rr[4] = {rv[k].x, rv[k].y, rv[k].z, rv[k].w};
    float gg[4] = {gv[k].x, gv[k].y, gv[k].z, gv[k].w};
    float bb[4] = {bv[k].x, bv[k].y, bv[k].z, bv[k].w};
    U32 pw[4][4];
    float w00[4], w01[4], w10[4], w11[4], drx[4];
    #pragma unroll
    for (int h = 0; h < 4; h++){
      float rq = rr[h] * 32.f;
      float gq = gg[h] * 32.f;
      float bq = bb[h] * 32.f;
      int ir = (int)rq; ir = ir > 31 ? 31 : ir;
      int ig = (int)gq; ig = ig > 31 ? 31 : ig;
      int ib = (int)bq; ib = ib > 31 ? 31 : ib;
      float dr = rq - (float)ir;
      float dg = gq - (float)ig;
      float db = bq - (float)ib;
      int lin = (ib*33 + ig)*33 + ir;
      pw[h][0] = ls[lin];
      pw[h][1] = ls[lin+33];
      pw[h][2] = ls[lin+1089];
      pw[h][3] = ls[lin+1122];
      float t = db*dg;
      w11[h] = t;
      w10[h] = db - t;
      w01[h] = dg - t;
      w00[h] = 1.f - db - dg + t;
      drx[h] = dr;
    }
    float res[4];
    #pragma unroll
    for (int h = 0; h < 4; h++){
      float odr = 1.f - drx[h];
      float v0 = odr*bflo2f(pw[h][0]) + drx[h]*bfhi2f(pw[h][0]);
      float v1 = odr*bflo2f(pw[h][1]) + drx[h]*bfhi2f(pw[h][1]);
      float v2 = odr*bflo2f(pw[h][2]) + drx[h]*bfhi2f(pw[h][2]);
      float v3 = odr*bflo2f(pw[h][3]) + drx[h]*bfhi2f(pw[h][3]);
      res[h] = w00[h]*v0 + w01[h]*v1 + w10[h]*v2 + w11[h]*v3;
    }
    *(float4*)(ob + base + k*4096) = make_float4(res[0], res[1], res[2], res[3]);
  }
}

__global__ void __launch_bounds__(1024, 4) ailut_apply_k(const float* __restrict__ x,
                                                         const U32* __restrict__ lp,
                                                         float* __restrict__ outp){
  __shared__ U32 ls[35936];             // 143744 B -> 1 block (16 waves) per CU
  int b = blockIdx.z, c = blockIdx.y;
  const size_t plane = 1048576;
  const float* xb = x + (size_t)b*3*plane;
  int base = blockIdx.x * 32768 + (int)threadIdx.x*4;
  float4 rv[4], gv[4], bv[4];
  #pragma unroll
  for (int k = 0; k < 4; k++){
    int p0 = base + k*4096;
    rv[k] = *(const float4*)(xb + p0);
    gv[k] = *(const float4*)(xb + plane + p0);
    bv[k] = *(const float4*)(xb + 2*plane + p0);
  }
  const U32* lsrc = lp + (size_t)(b*3 + c)*35940;
  for (int i = threadIdx.x; i < 8984; i += 1024)
    __builtin_amdgcn_global_load_lds(
        (const __attribute__((address_space(1))) void*)(lsrc + 4*(size_t)i),
        (__attribute__((address_space(3))) void*)(ls + 4*i), 16, 0, 0);
  __syncthreads();
  float* ob = outp + ((size_t)b*3 + c)*plane;
  apply_phase(ls, rv, gv, bv, ob, base);
  #pragma unroll
  for (int k = 0; k < 4; k++){
    int p0 = base + 16384 + k*4096;
    rv[k] = *(const float4*)(xb + p0);
    gv[k] = *(const float4*)(xb + plane + p0);
    bv[k] = *(const float4*)(xb + 2*plane + p0);
  }
  apply_phase(ls, rv, gv, bv, ob, base + 16384);
}

extern "C" void kernel_launch(void* const* d_in, const int* in_sizes, int n_in,
                              void* d_out, int out_size, void* d_ws, size_t ws_size,
                              hipStream_t stream){
  const float* x    = (const float*)d_in[0];
  const float* cw0  = (const float*)d_in[1];
  const float* cb0  = (const float*)d_in[2];
  const float* cw1  = (const float*)d_in[3];
  const float* cb1  = (const float*)d_in[4];
  const float* cw2  = (const float*)d_in[5];
  const float* cb2  = (const float*)d_in[6];
  const float* cw3  = (const float*)d_in[7];
  const float* cb3  = (const float*)d_in[8];
  const float* cw4  = (const float*)d_in[9];
  const float* cb4  = (const float*)d_in[10];
  const float* g0   = (const float*)d_in[11];
  const float* be0  = (const float*)d_in[12];
  const float* g1   = (const float*)d_in[13];
  const float* be1  = (const float*)d_in[14];
  const float* g2   = (const float*)d_in[15];
  const float* be2  = (const float*)d_in[16];
  const float* g3   = (const float*)d_in[17];
  const float* be3  = (const float*)d_in[18];
  const float* wgw  = (const float*)d_in[19];
  const float* wgb  = (const float*)d_in[20];
  const float* lutw = (const float*)d_in[21];
  const float* vert = (const float*)d_in[22];
  float* out = (float*)d_out;
  float* ws  = (float*)d_ws;

  // ws layout (floats): lp[862560 u32] | st0..st3 | resz | acts
  U32*   lp   = (U32*)ws;
  float* st0  = ws + 862720;            // 8*16*64*2  = 16384
  float* st1  = ws + 879104;            // 8*32*16*2  = 8192
  float* st2  = ws + 887296;            // 8*64*4*2   = 4096
  float* st3  = ws + 891392;            // 8*128*2*2  = 4096
  float* resz = ws + 895488;            // 1572864
  float* act0 = ws + 2468352;           // 2097152
  float* act1 = act0 + 2097152;         // 1048576
  float* act2 = act1 + 1048576;         // 524288
  float* act3 = act2 + 524288;          // 262144
  float* part = act3 + 262144;          // 768

  resize_k<<<1536, 256, 0, stream>>>(x, resz);

  conv0_k<<<512, 256, 0, stream>>>(resz, cw0, cb0, act0, st0);
  conv_leaky_k<16,32,128,64,8,1,64,16>
      <<<8*4*16, 256, 0, stream>>>(act0, cw1, cb1, act1, st0, g0, be0, st1);
  conv_leaky_k<32,64,64,32,4,1,16,4>
      <<<8*16*4, 256, 0, stream>>>(act1, cw2, cb2, act2, st1, g1, be1, st2);
  conv_leaky_k<64,128,32,16,4,2,4,2>
      <<<8*32*2, 256, 0, stream>>>(act2, cw3, cb3, act3, st2, g2, be2, st3);
  conv4_gemv_k<<<256, 256, 0, stream>>>(act3, cw4, cb4, st3, g3, be3, wgw, part);

  luts_k<<<422, 256, 0, stream>>>(part, wgb, lutw, vert, lp, out);
  ailut_apply_k<<<dim3(32,3,8), 1024, 0, stream>>>(x, lp, out);
}